// Round 1
// baseline (464.542 us; speedup 1.0000x reference)
//
#include <hip/hip_runtime.h>
#include <hip/hip_bf16.h>
#include <math.h>

// Problem: contrastive (NT-Xent-like) loss over x[16384][64] fp32.
//   x_hat = sqrt(2) * x / ||x||   (sqrt(2)^2 = 2 = 1/T folds the temperature)
//   den[j] = sum_i exp(x_hat_i . x_hat_j)   (includes diagonal; subtract e^2 later)
//   num[j] = exp(x_hat_{j^1} . x_hat_j)
//   out = -log( mean_j num[j] / (den[j] - e^2) )
// Compute-bound: N^2*K = 1.72e10 MAC on fp32 VALU (no fp32 MFMA) -> 219 us floor.

#define NROWS 16384
#define KDIM 64
#define TI 128
#define TJ 128

// ---- kernel A: row-normalize + prescale by sqrt(2) ------------------------
__global__ __launch_bounds__(256) void normalize_kernel(const float* __restrict__ x,
                                                        float* __restrict__ xn) {
    const int wave = threadIdx.x >> 6;
    const int lane = threadIdx.x & 63;
    const int row = blockIdx.x * 4 + wave;
    const float v = x[row * KDIM + lane];
    float ss = v * v;
    #pragma unroll
    for (int o = 32; o > 0; o >>= 1) ss += __shfl_xor(ss, o, 64);
    const float inv = 1.41421356237309515f * rsqrtf(fmaxf(ss, 1e-16f));
    xn[row * KDIM + lane] = v * inv;
}

// ---- kernel B: den[j] += sum over this block's i-tile of exp(2*sim) -------
// 128x128 tile, 256 threads, 8x8 acc/thread, K=64 in two 32-deep LDS passes.
__global__ __launch_bounds__(256) void den_kernel(const float* __restrict__ xn,
                                                  float* __restrict__ den) {
    __shared__ float As[32 * TI];  // [k][i], 16 KB
    __shared__ float Bs[32 * TJ];  // [k][j], 16 KB
    const int t = threadIdx.x;
    const int jb = blockIdx.x * TJ;
    const int ib = blockIdx.y * TI;
    const int tx = t & 15;   // j-group
    const int ty = t >> 4;   // i-group

    float acc[8][8];
    #pragma unroll
    for (int ii = 0; ii < 8; ii++)
        #pragma unroll
        for (int jj = 0; jj < 8; jj++) acc[ii][jj] = 0.0f;

    for (int p = 0; p < 2; p++) {
        // stage A (rows ib..ib+127) and B (rows jb..jb+127), k-chunk p*32..p*32+31,
        // transposed into LDS as [k][row].
        #pragma unroll
        for (int r = 0; r < 4; r++) {
            const int idx = t + 256 * r;   // 0..1023
            const int i = idx >> 3;        // 0..127
            const int kq = idx & 7;        // float4 index within 32 k's
            const float4 av = *(const float4*)&xn[(size_t)(ib + i) * KDIM + p * 32 + kq * 4];
            const float4 bv = *(const float4*)&xn[(size_t)(jb + i) * KDIM + p * 32 + kq * 4];
            As[(kq * 4 + 0) * TI + i] = av.x;
            As[(kq * 4 + 1) * TI + i] = av.y;
            As[(kq * 4 + 2) * TI + i] = av.z;
            As[(kq * 4 + 3) * TI + i] = av.w;
            Bs[(kq * 4 + 0) * TJ + i] = bv.x;
            Bs[(kq * 4 + 1) * TJ + i] = bv.y;
            Bs[(kq * 4 + 2) * TJ + i] = bv.z;
            Bs[(kq * 4 + 3) * TJ + i] = bv.w;
        }
        __syncthreads();
        #pragma unroll 4
        for (int k = 0; k < 32; k++) {
            float a[8], b[8];
            // A-frag: 4 distinct addresses/wave (ty spans 4 values) -> conflict-free
            *(float4*)&a[0] = *(const float4*)&As[k * TI + ty * 8];
            *(float4*)&a[4] = *(const float4*)&As[k * TI + ty * 8 + 4];
            // B-frag split (tx*4 and 64+tx*4): 2-way bank aliasing only (free per m136)
            *(float4*)&b[0] = *(const float4*)&Bs[k * TJ + tx * 4];
            *(float4*)&b[4] = *(const float4*)&Bs[k * TJ + 64 + tx * 4];
            #pragma unroll
            for (int ii = 0; ii < 8; ii++)
                #pragma unroll
                for (int jj = 0; jj < 8; jj++)
                    acc[ii][jj] = fmaf(a[ii], b[jj], acc[ii][jj]);
        }
        __syncthreads();
    }

    // epilogue: exp + per-thread column partial sums (8 i's each)
    float cs[8];
    #pragma unroll
    for (int jj = 0; jj < 8; jj++) {
        float s = 0.0f;
        #pragma unroll
        for (int ii = 0; ii < 8; ii++) s += __expf(acc[ii][jj]);
        cs[jj] = s;
    }
    // reduce across the 16 ty-groups through LDS (reuse As; all compute reads are
    // behind the final __syncthreads above)
    float* red = As;  // needs 16*TJ = 2048 floats, As has 4096
    #pragma unroll
    for (int jj = 0; jj < 8; jj++) {
        const int jcol = (jj < 4) ? (tx * 4 + jj) : (64 + tx * 4 + (jj - 4));
        red[ty * TJ + jcol] = cs[jj];
    }
    __syncthreads();
    if (t < TJ) {
        float s = 0.0f;
        #pragma unroll
        for (int ty2 = 0; ty2 < 16; ty2++) s += red[ty2 * TJ + t];
        atomicAdd(&den[jb + t], s);
    }
}

// ---- kernel C: num/den ratio + global sum ---------------------------------
__global__ __launch_bounds__(256) void num_kernel(const float* __restrict__ xn,
                                                  const float* __restrict__ den,
                                                  float* __restrict__ accum) {
    const int j = blockIdx.x * 256 + threadIdx.x;
    const int pj = j ^ 1;  // adjacent-row partner
    float dot = 0.0f;
    #pragma unroll
    for (int kq = 0; kq < 16; kq++) {
        const float4 a = *(const float4*)&xn[(size_t)j * KDIM + kq * 4];
        const float4 b = *(const float4*)&xn[(size_t)pj * KDIM + kq * 4];
        dot = fmaf(a.x, b.x, dot);
        dot = fmaf(a.y, b.y, dot);
        dot = fmaf(a.z, b.z, dot);
        dot = fmaf(a.w, b.w, dot);
    }
    const float E2 = 7.38905609893065f;  // exp(1/T) = exp(2)
    float r = __expf(dot) / (den[j] - E2);
    #pragma unroll
    for (int o = 32; o > 0; o >>= 1) r += __shfl_xor(r, o, 64);
    __shared__ float wsum[4];
    if ((threadIdx.x & 63) == 0) wsum[threadIdx.x >> 6] = r;
    __syncthreads();
    if (threadIdx.x == 0) atomicAdd(accum, wsum[0] + wsum[1] + wsum[2] + wsum[3]);
}

// ---- kernel D: final scalar ----------------------------------------------
__global__ void final_kernel(const float* __restrict__ accum, float* __restrict__ out) {
    out[0] = -logf(accum[0] / (float)NROWS);
}

extern "C" void kernel_launch(void* const* d_in, const int* in_sizes, int n_in,
                              void* d_out, int out_size, void* d_ws, size_t ws_size,
                              hipStream_t stream) {
    const float* x = (const float*)d_in[0];
    float* out = (float*)d_out;

    // ws layout: xn [16384*64 f32 = 4 MB] | den [16384 f32] | accum [1 f32]
    float* xn = (float*)d_ws;
    float* den = xn + (size_t)NROWS * KDIM;
    float* accum = den + NROWS;

    hipMemsetAsync(den, 0, (NROWS + 1) * sizeof(float), stream);
    normalize_kernel<<<NROWS / 4, 256, 0, stream>>>(x, xn);
    den_kernel<<<dim3(NROWS / TJ, NROWS / TI), 256, 0, stream>>>(xn, den);
    num_kernel<<<NROWS / 256, 256, 0, stream>>>(xn, den, accum);
    final_kernel<<<1, 1, 0, stream>>>(accum, out);
}

// Round 2
// 150.827 us; speedup vs baseline: 3.0800x; 3.0800x over previous
//
#include <hip/hip_runtime.h>
#include <hip/hip_bf16.h>
#include <math.h>

// Contrastive (NT-Xent-like) loss over x[16384][64] fp32.
//   x_hat = sqrt(2) * x / ||x||   (sqrt(2)^2 = 2 = 1/T folds the temperature)
//   den[j] = sum_i exp(x_hat_i . x_hat_j) - e^2
//   num[j] = exp(x_hat_{j^1} . x_hat_j)   (computed in exact fp32 from raw x)
//   out = -log( mean_j num[j] / den[j] )
// Round 2: sim GEMM moved from fp32 VALU (LDS-BW + VALU co-limited, 442 us)
// to bf16 MFMA 16x16x32 (~14 us MFMA floor; exp epilogue ~14 us floor).
// Threshold is 0.19375 abs; bf16 rounding of x_hat costs ~3e-3 on the loss.

#define NROWS 16384
#define KDIM 64
#define TI 128
#define TJ 128

typedef __attribute__((ext_vector_type(8))) short short8;   // 8 bf16 = 4 VGPRs
typedef __attribute__((ext_vector_type(4))) float f32x4;

// ---- kernel A: row-normalize + prescale by sqrt(2), emit bf16 -------------
__global__ __launch_bounds__(256) void normalize_kernel(const float* __restrict__ x,
                                                        __hip_bfloat16* __restrict__ xnb) {
    const int wave = threadIdx.x >> 6;
    const int lane = threadIdx.x & 63;
    const int row = blockIdx.x * 4 + wave;
    const float v = x[row * KDIM + lane];
    float ss = v * v;
    #pragma unroll
    for (int o = 32; o > 0; o >>= 1) ss += __shfl_xor(ss, o, 64);
    const float inv = 1.41421356237309515f * rsqrtf(fmaxf(ss, 1e-16f));
    xnb[row * KDIM + lane] = __float2bfloat16(v * inv);
}

// ---- kernel B: den[j] += colsum_i exp(x_hat_i . x_hat_j) ------------------
// 128x128 block tile, 4 waves (2x2), 64x64 per wave, mfma_f32_16x16x32_bf16.
// LDS layout = fragment-chunk order: chunk(mt,kc,quad,m) at
//   pos = ((mt*2+kc)*64 + quad*16 + m) * 16B
// holds row (base+mt*16+m), bf16 k = kc*32+quad*8 .. +8. Lane (quad*16+m)
// then reads its MFMA A/B fragment as ds_read_b128 at uniform + lane*16.
__global__ __launch_bounds__(256) void den_kernel(const __hip_bfloat16* __restrict__ xnb,
                                                  float* __restrict__ den) {
    __shared__ unsigned short As[8192];  // 1024 chunks * 16 B = 16 KB
    __shared__ unsigned short Bs[8192];
    __shared__ float red[2 * TJ];

    const int t = threadIdx.x;
    const int jb = blockIdx.x * TJ;
    const int ib = blockIdx.y * TI;

    // stage: global chunk g = (row r)*8 + kq  ->  LDS chunk pos(r, kq).
    // Global side: 8 consecutive lanes cover one full 128-B row (coalesced).
    // LDS side: lanes' pos%8 = r%8 uniform over 8 values -> natural b128 pattern.
    #pragma unroll
    for (int s = 0; s < 4; s++) {
        const int g = s * 256 + t;         // 0..1023
        const int r = g >> 3;              // row within tile
        const int kq = g & 7;              // 16-B chunk within row
        const int pos = ((r >> 4) * 2 + (kq >> 2)) * 64 + (kq & 3) * 16 + (r & 15);
        const float4 av = *(const float4*)((const char*)xnb + ((size_t)(ib + r) * KDIM + kq * 8) * 2);
        const float4 bv = *(const float4*)((const char*)xnb + ((size_t)(jb + r) * KDIM + kq * 8) * 2);
        *(float4*)&As[pos * 8] = av;
        *(float4*)&Bs[pos * 8] = bv;
    }
    __syncthreads();

    const int w = t >> 6;
    const int lane = t & 63;
    const int wi = w >> 1;   // 0..1: i-half of the block tile
    const int wj = w & 1;    // 0..1: j-half

    const f32x4 zero = {0.f, 0.f, 0.f, 0.f};
    f32x4 acc[4][4];
    #pragma unroll
    for (int it = 0; it < 4; it++)
        #pragma unroll
        for (int jt = 0; jt < 4; jt++) acc[it][jt] = zero;

    #pragma unroll
    for (int kc = 0; kc < 2; kc++) {
        short8 af[4], bf[4];
        #pragma unroll
        for (int it = 0; it < 4; it++)
            af[it] = *(const short8*)&As[((((wi * 4 + it) * 2 + kc) * 64) + lane) * 8];
        #pragma unroll
        for (int jt = 0; jt < 4; jt++)
            bf[jt] = *(const short8*)&Bs[((((wj * 4 + jt) * 2 + kc) * 64) + lane) * 8];
        #pragma unroll
        for (int it = 0; it < 4; it++)
            #pragma unroll
            for (int jt = 0; jt < 4; jt++)
                acc[it][jt] = __builtin_amdgcn_mfma_f32_16x16x32_bf16(af[it], bf[jt], acc[it][jt], 0, 0, 0);
    }

    // epilogue: exp + column sums. C/D layout: col=lane&15, row=(lane>>4)*4+reg.
    float cs[4];
    #pragma unroll
    for (int jt = 0; jt < 4; jt++) {
        float s = 0.0f;
        #pragma unroll
        for (int it = 0; it < 4; it++) {
            s += __expf(acc[it][jt][0]);
            s += __expf(acc[it][jt][1]);
            s += __expf(acc[it][jt][2]);
            s += __expf(acc[it][jt][3]);
        }
        cs[jt] = s;
    }
    #pragma unroll
    for (int jt = 0; jt < 4; jt++) {
        cs[jt] += __shfl_xor(cs[jt], 16, 64);  // sum over quad bit 0
        cs[jt] += __shfl_xor(cs[jt], 32, 64);  // sum over quad bit 1
    }
    if (lane < 16) {
        #pragma unroll
        for (int jt = 0; jt < 4; jt++)
            red[wi * TJ + wj * 64 + jt * 16 + lane] = cs[jt];
    }
    __syncthreads();
    if (t < TJ) atomicAdd(&den[jb + t], red[t] + red[TJ + t]);
}

// ---- kernel C: num/den ratio + global sum (exact fp32 from raw x) ---------
__global__ __launch_bounds__(256) void num_kernel(const float* __restrict__ x,
                                                  const float* __restrict__ den,
                                                  float* __restrict__ accum) {
    const int j = blockIdx.x * 256 + threadIdx.x;
    const int pj = j ^ 1;  // adjacent-row partner
    float dot = 0.0f, sa = 0.0f, sb = 0.0f;
    #pragma unroll
    for (int kq = 0; kq < 16; kq++) {
        const float4 a = *(const float4*)&x[(size_t)j * KDIM + kq * 4];
        const float4 b = *(const float4*)&x[(size_t)pj * KDIM + kq * 4];
        dot = fmaf(a.x, b.x, fmaf(a.y, b.y, fmaf(a.z, b.z, fmaf(a.w, b.w, dot))));
        sa = fmaf(a.x, a.x, fmaf(a.y, a.y, fmaf(a.z, a.z, fmaf(a.w, a.w, sa))));
        sb = fmaf(b.x, b.x, fmaf(b.y, b.y, fmaf(b.z, b.z, fmaf(b.w, b.w, sb))));
    }
    const float sim = 2.0f * dot / fmaxf(sqrtf(sa * sb), 1e-8f);
    const float E2 = 7.38905609893065f;  // exp(1/T) = exp(2): diagonal removal
    float r = __expf(sim) / (den[j] - E2);
    #pragma unroll
    for (int o = 32; o > 0; o >>= 1) r += __shfl_xor(r, o, 64);
    __shared__ float wsum[4];
    if ((threadIdx.x & 63) == 0) wsum[threadIdx.x >> 6] = r;
    __syncthreads();
    if (threadIdx.x == 0) atomicAdd(accum, wsum[0] + wsum[1] + wsum[2] + wsum[3]);
}

// ---- kernel D: final scalar ----------------------------------------------
__global__ void final_kernel(const float* __restrict__ accum, float* __restrict__ out) {
    out[0] = -logf(accum[0] / (float)NROWS);
}

extern "C" void kernel_launch(void* const* d_in, const int* in_sizes, int n_in,
                              void* d_out, int out_size, void* d_ws, size_t ws_size,
                              hipStream_t stream) {
    const float* x = (const float*)d_in[0];
    float* out = (float*)d_out;

    // ws layout: xnb [16384*64 bf16 = 2 MB] | den [16384 f32] | accum [1 f32]
    __hip_bfloat16* xnb = (__hip_bfloat16*)d_ws;
    float* den = (float*)((char*)d_ws + (size_t)NROWS * KDIM * sizeof(__hip_bfloat16));
    float* accum = den + NROWS;

    hipMemsetAsync(den, 0, (NROWS + 1) * sizeof(float), stream);
    normalize_kernel<<<NROWS / 4, 256, 0, stream>>>(x, xnb);
    den_kernel<<<dim3(NROWS / TJ, NROWS / TI), 256, 0, stream>>>(xnb, den);
    num_kernel<<<NROWS / 256, 256, 0, stream>>>(x, den, accum);
    final_kernel<<<1, 1, 0, stream>>>(accum, out);
}